// Round 10
// baseline (561.769 us; speedup 1.0000x reference)
//
#include <hip/hip_runtime.h>

typedef unsigned long long u64;
typedef unsigned int u32;
typedef float v2f __attribute__((ext_vector_type(2)));

// Problem constants (from reference setup_inputs / NUM_GROUP / GROUP_SIZE)
#define BATCH 32
#define NPTS  8192
#define NGRP  512
#define KNN_K 32

#define FPS_T 256                  // fps block (4 waves) -- champion config
#define FPS_W (FPS_T / 64)         // 4 waves
#define PPAIR (NPTS / FPS_T / 2)   // 16 point-PAIRS per thread

#define KNN_WPB 8                  // knn waves per block
#define KNN_T   (KNN_WPB * 64)     // 512 threads
#define QCAP    128                // per-wave LDS candidate buffer depth

#define NCH     (NPTS / 64)        // 128 sorted 64-point chunks per batch
#define GC      16                 // grid cells per axis (16^3 = 4096)
#define NCELL   (GC * GC * GC)
#define QB      512                // quantile-CDF bins per axis
#define BT      512                // build_kernel threads
#define BPT     (NPTS / BT)        // 16 points per build thread
// Workspace layout per batch (floats): sx[8192] sy[8192] sz[8192] sidx[8192(u32)] aabb[128*6]
#define WSF     (4 * NPTS + NCH * 6)   // 33536 floats per batch

// Exact IEEE (no FMA contraction) squared distance: ((dx*dx + dy*dy) + dz*dz)
__device__ __forceinline__ float sq3(float dx, float dy, float dz) {
    return __fadd_rn(__fadd_rn(__fmul_rn(dx, dx), __fmul_rn(dy, dy)), __fmul_rn(dz, dz));
}

// d >= 0 always -> IEEE bits order-monotonic; u64 ascending == (d, idx) lex.
__device__ __forceinline__ u64 packdi(float d, int n) {
    return ((u64)__float_as_uint(d) << 32) | (u32)n;
}

__device__ __forceinline__ u64 umin64(u64 a, u64 b) { return a < b ? a : b; }
__device__ __forceinline__ u64 umax64(u64 a, u64 b) { return a > b ? a : b; }

__device__ __forceinline__ u64 shfl_xor_u64(u64 v, int m) {
    int lo = __shfl_xor((int)(u32)v, m, 64);
    int hi = __shfl_xor((int)(u32)(v >> 32), m, 64);
    return ((u64)(u32)hi << 32) | (u32)lo;
}

__device__ __forceinline__ u64 shfl_u64(u64 v, int src) {
    int lo = __shfl((int)(u32)v, src, 64);
    int hi = __shfl((int)(u32)(v >> 32), src, 64);
    return ((u64)(u32)hi << 32) | (u32)lo;
}

// ---- DPP wave-64 u64-max reduction (result valid in lane 63) --------------
// update_dpp(old=0, bound_ctrl=1): invalid-source lanes read 0; 0 is a safe
// identity (keys are max-reduced; 0 never beats a real candidate).
template <int CTRL>
__device__ __forceinline__ u64 dpp_max_step(u64 k) {
    u32 plo = (u32)__builtin_amdgcn_update_dpp(0, (int)(u32)k, CTRL, 0xF, 0xF, true);
    u32 phi = (u32)__builtin_amdgcn_update_dpp(0, (int)(u32)(k >> 32), CTRL, 0xF, 0xF, true);
    u64 p = ((u64)phi << 32) | plo;
    return k > p ? k : p;
}
__device__ __forceinline__ u64 dpp_wave_max(u64 k) {
    k = dpp_max_step<0x111>(k);  // row_shr:1
    k = dpp_max_step<0x112>(k);  // row_shr:2
    k = dpp_max_step<0x114>(k);  // row_shr:4
    k = dpp_max_step<0x118>(k);  // row_shr:8
    k = dpp_max_step<0x142>(k);  // row_bcast15
    k = dpp_max_step<0x143>(k);  // row_bcast31 -> lane63 = full wave
    return k;
}

// Cross-lane bitonic sort: one u64 per lane -> ascending by lane index.
__device__ __forceinline__ u64 lane_sort64(u64 v, int lane) {
#pragma unroll
    for (int k = 2; k <= 64; k <<= 1) {
#pragma unroll
        for (int j = k >> 1; j > 0; j >>= 1) {
            u64 p = shfl_xor_u64(v, j);
            bool keepmin = (((lane & k) == 0) == ((lane & j) == 0));
            u64 mn = umin64(v, p), mx = umax64(v, p);
            v = keepmin ? mn : mx;
        }
    }
    return v;
}

// m, c ascending-sorted across lanes -> lowest 64 of the 128, sorted.
__device__ __forceinline__ u64 lane_merge64(u64 m, u64 c, int lane) {
    u64 cr = shfl_xor_u64(c, 63);
    u64 z = umin64(m, cr);
#pragma unroll
    for (int dd = 32; dd > 0; dd >>= 1) {
        u64 p = shfl_xor_u64(z, dd);
        u64 mn = umin64(z, p), mx = umax64(z, p);
        z = (lane & dd) ? mx : mn;
    }
    return z;
}

// One knn scan step: tau-filter + ballot-compacted LDS append + batched flush
__device__ __forceinline__ void knn_step(u64& m, u64& tau, int& cnt, u64* sbuf,
                                         float x, float y, float z,
                                         float cx, float cy, float cz,
                                         int n, int lane) {
    float d = sq3(__fsub_rn(x, cx), __fsub_rn(y, cy), __fsub_rn(z, cz));
    u64 kk = packdi(d, n);
    bool cand = kk < tau;  // strict: excluded keys provably > global 32nd
    u64 mask = __ballot(cand);
    if (mask) {
        u32 below = __builtin_amdgcn_mbcnt_hi(
            (u32)(mask >> 32), __builtin_amdgcn_mbcnt_lo((u32)mask, 0));
        if (cand) sbuf[cnt + below] = kk;
        cnt += (int)__popcll(mask);
        if (cnt >= 64) {
            u64 c = sbuf[lane];
            c = lane_sort64(c, lane);
            m = lane_merge64(m, c, lane);
            tau = shfl_u64(m, 31);
            int rem = cnt - 64;
            if (lane < rem) sbuf[lane] = sbuf[64 + lane];
            cnt = rem;
        }
    }
}

// ---------------------------------------------------------------------------
// FPS (champion, 418 us): one block per batch, 256 threads, 32 points/thread
// as 16 float2 pairs (contract(off): per-op IEEE rounding == numpy). In-loop
// strict-> (bd,bi) tracking per half; u64 (d_bits,~n) pack, 6-step DPP wave
// argmax, single barrier, double-buffered 4-partial exchange, scalar b32
// coord broadcasts, LDS-buffered centers. 9+ alternative structures across
// two sessions (incl. R5 sorted-skip 1371us; R6/R8 fused 2030/2238us --
// VGPR spill to 88, launch_bounds(512,1) did NOT fix, mechanism unresolved
// without disasm) all regressed -- DO NOT restructure this kernel.
// UNCHANGED this round (isolated knn instruction-count experiment).
// ---------------------------------------------------------------------------
__global__ __launch_bounds__(FPS_T) void fps_kernel(const float* __restrict__ in,
                                                    float* __restrict__ centers) {
#pragma clang fp contract(off)
    __shared__ float sx[NPTS];           // 32 KB
    __shared__ float sy[NPTS];           // 32 KB
    __shared__ float sz[NPTS];           // 32 KB
    __shared__ u64 s_key[2][FPS_W];      // double-buffered wave partials
    __shared__ float s_out[NGRP * 3];    // 6 KB center-coord buffer

    const int b = blockIdx.x;
    const int t = threadIdx.x;
    const int w = t >> 6;
    const float* xp = in + (size_t)b * 3 * NPTS;
    const float* yp = xp + NPTS;
    const float* zp = xp + 2 * NPTS;

    v2f xr[PPAIR], yr[PPAIR], zr[PPAIR], md[PPAIR];
#pragma unroll
    for (int i = 0; i < PPAIR; ++i) {
        int n = i * (2 * FPS_T) + 2 * t;       // pair covers points n, n+1
        xr[i] = *(const v2f*)(xp + n);
        yr[i] = *(const v2f*)(yp + n);
        zr[i] = *(const v2f*)(zp + n);
        *(v2f*)(sx + n) = xr[i];
        *(v2f*)(sy + n) = yr[i];
        *(v2f*)(sz + n) = zr[i];
        md[i] = (v2f){1e10f, 1e10f};
    }
    __syncthreads();

    int cur = 0;
    for (int r = 0; r < NGRP; ++r) {
        const float cx = sx[cur], cy = sy[cur], cz = sz[cur];  // b32 broadcasts
        if (t == 0) {  // idxs[r] is the PRE-update farthest -> buffer coords
            s_out[r * 3 + 0] = cx;
            s_out[r * 3 + 1] = cy;
            s_out[r * 3 + 2] = cz;
        }

        float bd0 = -1.0f, bd1 = -1.0f;
        int   bi0 = 0,     bi1 = 0;
#pragma unroll
        for (int i = 0; i < PPAIR; ++i) {
            v2f dx = xr[i] - cx;
            v2f dy = yr[i] - cy;
            v2f dz = zr[i] - cz;
            v2f dd = dx * dx + dy * dy + dz * dz;  // contract(off): 3 mul + 2 add
            md[i] = __builtin_elementwise_min(md[i], dd);
            int n = i * (2 * FPS_T) + 2 * t;
            if (md[i].x > bd0) { bd0 = md[i].x; bi0 = n; }      // strict >: first max
            if (md[i].y > bd1) { bd1 = md[i].y; bi1 = n + 1; }
        }
        // max (d, tie -> lowest n) == u64 max of (d_bits, ~n)
        u64 k0 = ((u64)__float_as_uint(bd0) << 32) | (u32)(~(u32)bi0);
        u64 k1 = ((u64)__float_as_uint(bd1) << 32) | (u32)(~(u32)bi1);
        u64 k = dpp_wave_max(umax64(k0, k1));
        if ((t & 63) == 63) s_key[r & 1][w] = k;  // lane 63 holds wave winner
        __syncthreads();
        u64 m = umax64(umax64(s_key[r & 1][0], s_key[r & 1][1]),
                       umax64(s_key[r & 1][2], s_key[r & 1][3]));
        cur = (int)(~(u32)m);  // recover winning index
    }

    __syncthreads();  // t0's last s_out writes
    float* cdst = centers + (size_t)b * NGRP * 3;
    for (int i = t; i < NGRP * 3; i += FPS_T) cdst[i] = s_out[i];
}

// ---------------------------------------------------------------------------
// build_kernel (R4 champion, UNCHANGED): quantile-warped Morton counting-sort
// + per-chunk AABBs. Ordering-only -> output bits unaffected.
// ---------------------------------------------------------------------------
__device__ __forceinline__ int qbin(float v) {  // 512 bins over [-4,4]
    int c = (int)((v + 4.0f) * 64.0f);
    c = c < 0 ? 0 : c;
    return c > (QB - 1) ? (QB - 1) : c;
}
__device__ __forceinline__ u32 part3_4(u32 v) {  // spread 4 bits to bits 0,3,6,9
    return (v & 1u) | ((v & 2u) << 2) | ((v & 4u) << 4) | ((v & 8u) << 6);
}

__global__ __launch_bounds__(BT) void build_kernel(const float* __restrict__ in,
                                                   float* __restrict__ ws) {
    __shared__ u32 hist[NCELL];     // 16 KB
    __shared__ u32 hq[3][QB];       // 6 KB axis histograms -> cell LUTs
    __shared__ float sxl[NPTS];     // 32 KB
    __shared__ float syl[NPTS];     // 32 KB
    __shared__ float szl[NPTS];     // 32 KB  (total ~118 KB; 1 block/CU, fine)
    __shared__ u32 wtot[3][BT / 64];

    const int b = blockIdx.x;
    const int t = threadIdx.x;
    const int lane = t & 63;
    const int w = t >> 6;
    const float* xp = in + (size_t)b * 3 * NPTS;
    const float* yp = xp + NPTS;
    const float* zp = xp + 2 * NPTS;
    float* wsb = ws + (size_t)b * WSF;
    float* ws_sx = wsb;
    float* ws_sy = wsb + NPTS;
    float* ws_sz = wsb + 2 * NPTS;
    u32*   ws_si = (u32*)(wsb + 3 * NPTS);
    float* ws_ab = wsb + 4 * NPTS;

    for (int i = t; i < NCELL; i += BT) hist[i] = 0;
    for (int i = t; i < 3 * QB; i += BT) (&hq[0][0])[i] = 0;
    __syncthreads();

    // load points (kept in regs for the whole kernel) + per-axis histograms
    float px[BPT], py[BPT], pz[BPT];
#pragma unroll
    for (int i = 0; i < BPT; ++i) {
        int n = i * BT + t;  // coalesced
        px[i] = xp[n]; py[i] = yp[n]; pz[i] = zp[n];
        atomicAdd(&hq[0][qbin(px[i])], 1u);
        atomicAdd(&hq[1][qbin(py[i])], 1u);
        atomicAdd(&hq[2][qbin(pz[i])], 1u);
    }
    __syncthreads();

    // exclusive-scan each 512-bin histogram (1 bin/thread), then convert in
    // place to a quantile-cell LUT: cell = excl_cdf >> 9  (16 x 512-pt slices)
    {
        u32 v0 = hq[0][t], v1 = hq[1][t], v2 = hq[2][t];
        u32 x0 = v0, x1 = v1, x2 = v2;
#pragma unroll
        for (int d = 1; d < 64; d <<= 1) {
            u32 y0 = __shfl_up(x0, d, 64), y1 = __shfl_up(x1, d, 64), y2 = __shfl_up(x2, d, 64);
            if (lane >= d) { x0 += y0; x1 += y1; x2 += y2; }
        }
        if (lane == 63) { wtot[0][w] = x0; wtot[1][w] = x1; wtot[2][w] = x2; }
        __syncthreads();
        u32 b0 = 0, b1 = 0, b2 = 0;
        for (int j = 0; j < w; ++j) { b0 += wtot[0][j]; b1 += wtot[1][j]; b2 += wtot[2][j]; }
        hq[0][t] = (b0 + x0 - v0) >> 9;   // <= 8191>>9 = 15, always 4-bit
        hq[1][t] = (b1 + x1 - v1) >> 9;
        hq[2][t] = (b2 + x2 - v2) >> 9;
    }
    __syncthreads();

    // Morton code on warped cells + counting histogram
    int pc[BPT];
#pragma unroll
    for (int i = 0; i < BPT; ++i) {
        u32 cxq = hq[0][qbin(px[i])];
        u32 cyq = hq[1][qbin(py[i])];
        u32 czq = hq[2][qbin(pz[i])];
        pc[i] = (int)(part3_4(cxq) | (part3_4(cyq) << 1) | (part3_4(czq) << 2));
        atomicAdd(&hist[pc[i]], 1u);
    }
    __syncthreads();

    // exclusive scan of hist[4096]: 8 cells/thread + wave scan + cross-wave
    u32 h[NCELL / BT];
    u32 lsum = 0;
#pragma unroll
    for (int j = 0; j < NCELL / BT; ++j) { h[j] = hist[t * (NCELL / BT) + j]; lsum += h[j]; }
    u32 x = lsum;
#pragma unroll
    for (int d = 1; d < 64; d <<= 1) {
        u32 y = __shfl_up(x, d, 64);
        if (lane >= d) x += y;
    }
    if (lane == 63) wtot[0][w] = x;
    u32 wexcl = x - lsum;
    __syncthreads();
    u32 base = 0;
    for (int j = 0; j < w; ++j) base += wtot[0][j];
    u32 run = base + wexcl;
#pragma unroll
    for (int j = 0; j < NCELL / BT; ++j) {
        u32 c = h[j];
        hist[t * (NCELL / BT) + j] = run;
        run += c;
    }
    __syncthreads();

    // scatter into LDS (coords) + global (orig index)
#pragma unroll
    for (int i = 0; i < BPT; ++i) {
        u32 pos = atomicAdd(&hist[pc[i]], 1u);
        sxl[pos] = px[i]; syl[pos] = py[i]; szl[pos] = pz[i];
        ws_si[pos] = (u32)(i * BT + t);
    }
    __syncthreads();

    // write sorted coords out, coalesced
    for (int i = t; i < NPTS; i += BT) {
        ws_sx[i] = sxl[i]; ws_sy[i] = syl[i]; ws_sz[i] = szl[i];
    }
    // per-chunk AABB: 128 chunks / 8 waves
    for (int q = w; q < NCH; q += BT / 64) {
        int p = q * 64 + lane;
        float X = sxl[p], Y = syl[p], Z = szl[p];
        float xlo = X, xhi = X, ylo = Y, yhi = Y, zlo = Z, zhi = Z;
#pragma unroll
        for (int d = 1; d < 64; d <<= 1) {
            xlo = fminf(xlo, __shfl_xor(xlo, d, 64)); xhi = fmaxf(xhi, __shfl_xor(xhi, d, 64));
            ylo = fminf(ylo, __shfl_xor(ylo, d, 64)); yhi = fmaxf(yhi, __shfl_xor(yhi, d, 64));
            zlo = fminf(zlo, __shfl_xor(zlo, d, 64)); zhi = fmaxf(zhi, __shfl_xor(zhi, d, 64));
        }
        if (lane == 0) {
            float* a = ws_ab + q * 6;
            a[0] = xlo; a[1] = xhi; a[2] = ylo; a[3] = yhi; a[4] = zlo; a[5] = zhi;
        }
    }
}

// ---------------------------------------------------------------------------
// kNN v4: static sorted chunk order. R9's loop paid a ~50-op u64 DPP argmin
// PER CHUNK VISITED; at full occupancy (small LDS -> ~32 waves/CU) knn is
// VALU-issue bound, so that op count is the wall time. v4 sorts all 128
// (lb,chunk) keys ONCE (2x lane_sort64 + both-halves bitonic merge, ~450
// ops) into lo=ranks 0..63 / hi=ranks 64..127, then iterates with one shfl
// per chunk (~8 ops). u64-ascending order == (lb, chunk-id) lex == R9's
// DPP-pick order EXACTLY -> identical tau evolution, identical break point,
// identical output bits. Pure instruction-count reduction.
// ---------------------------------------------------------------------------
__global__ __launch_bounds__(KNN_T) void knn_kernel(const float* __restrict__ in,
                                                    const float* __restrict__ centers,
                                                    const float* __restrict__ ws,
                                                    float* __restrict__ out) {
    __shared__ float s_ab[NCH * 6];      // 3 KB chunk AABBs (whole block same batch)
    __shared__ u64 sbuf[KNN_WPB][QCAP];  // 8 KB candidate buffers

    const int wave = threadIdx.x >> 6;
    const int lane = threadIdx.x & 63;
    const int cid  = blockIdx.x * KNN_WPB + wave;   // [0, B*G); 8 waves same batch
    const int b    = cid >> 9;                      // /NGRP

    const float* xp = in + (size_t)b * 3 * NPTS;
    const float* yp = xp + NPTS;
    const float* zp = xp + 2 * NPTS;
    const float* wsb = ws + (size_t)b * WSF;
    const float* sxs = wsb;
    const float* sys = wsb + NPTS;
    const float* szs = wsb + 2 * NPTS;
    const u32*   sidx = (const u32*)(wsb + 3 * NPTS);
    const float* ab = wsb + 4 * NPTS;

    for (int i = threadIdx.x; i < NCH * 6; i += KNN_T) s_ab[i] = ab[i];
    __syncthreads();

    const float cx = centers[cid * 3 + 0];
    const float cy = centers[cid * 3 + 1];
    const float cz = centers[cid * 3 + 2];

    // per-lane lower-bound keys for chunks lane and lane+64
    u64 k0, k1;
    {
        const float* a0 = &s_ab[lane * 6];
        float dx = fmaxf(fmaxf(__fsub_rn(a0[0], cx), __fsub_rn(cx, a0[1])), 0.0f);
        float dy = fmaxf(fmaxf(__fsub_rn(a0[2], cy), __fsub_rn(cy, a0[3])), 0.0f);
        float dz = fmaxf(fmaxf(__fsub_rn(a0[4], cz), __fsub_rn(cz, a0[5])), 0.0f);
        k0 = ((u64)__float_as_uint(dx * dx + dy * dy + dz * dz) << 32) | (u32)lane;
        const float* a1 = &s_ab[(lane + 64) * 6];
        dx = fmaxf(fmaxf(__fsub_rn(a1[0], cx), __fsub_rn(cx, a1[1])), 0.0f);
        dy = fmaxf(fmaxf(__fsub_rn(a1[2], cy), __fsub_rn(cy, a1[3])), 0.0f);
        dz = fmaxf(fmaxf(__fsub_rn(a1[4], cz), __fsub_rn(cz, a1[5])), 0.0f);
        k1 = ((u64)__float_as_uint(dx * dx + dy * dy + dz * dz) << 32) | (u32)(lane + 64);
    }

    // sort all 128 keys ascending once: lo = ranks 0..63, hi = ranks 64..127
    u64 lo, hi;
    {
        k0 = lane_sort64(k0, lane);
        k1 = lane_sort64(k1, lane);
        u64 c1r = shfl_xor_u64(k1, 63);   // reverse k1
        lo = umin64(k0, c1r);             // bitonic split: max(lo) <= min(hi)
        hi = umax64(k0, c1r);
#pragma unroll
        for (int dd = 32; dd > 0; dd >>= 1) {   // merge each bitonic half
            u64 pl = shfl_xor_u64(lo, dd);
            u64 ph = shfl_xor_u64(hi, dd);
            u64 lmn = umin64(lo, pl), lmx = umax64(lo, pl);
            u64 hmn = umin64(hi, ph), hmx = umax64(hi, ph);
            lo = (lane & dd) ? lmx : lmn;
            hi = (lane & dd) ? hmx : hmn;
        }
    }

    u64 m, tau;
    int cnt = 0;

    // seed: rank-0 (nearest) chunk, exact sorted top-64
    {
        u64 key = shfl_u64(lo, 0);
        int c = (int)(u32)key;
        int p = c * 64 + lane;
        float X = sxs[p], Y = sys[p], Z = szs[p];
        int n = (int)sidx[p];
        m = lane_sort64(packdi(sq3(__fsub_rn(X, cx), __fsub_rn(Y, cy), __fsub_rn(Z, cz)), n),
                        lane);
        tau = shfl_u64(m, 31);
    }

    // stream chunks in ascending-lb order; sound early break
    for (int r = 1; r < NCH; ++r) {
        u64 key = (r < 64) ? shfl_u64(lo, r) : shfl_u64(hi, r - 64);
        float lb = __uint_as_float((u32)(key >> 32));
        float tau_d = __uint_as_float((u32)(tau >> 32));
        if (lb * 0.999f > tau_d) break;  // all remaining chunks provably > 32nd
        int c = (int)(u32)key;
        int p = c * 64 + lane;
        float X = sxs[p], Y = sys[p], Z = szs[p];
        int n = (int)sidx[p];
        knn_step(m, tau, cnt, sbuf[wave], X, Y, Z, cx, cy, cz, n, lane);
    }

    // drain leftovers (<= 127 keys -> at most 2 batches)
    while (cnt > 0) {
        int take = cnt < 64 ? cnt : 64;
        u64 v = sbuf[wave][lane];
        u64 c = (lane < take) ? v : ~0ull;
        c = lane_sort64(c, lane);
        m = lane_merge64(m, c, lane);
        int rem = cnt - take;
        if (lane < rem) sbuf[wave][lane] = sbuf[wave][64 + lane];
        cnt = rem;
    }

    // lanes 0..31 hold the exact global top-32, ascending (== stable top_k)
    if (lane < KNN_K) {
        int n = (int)(u32)m;
        size_t o = (size_t)cid * (KNN_K * 3) + (size_t)lane * 3;
        out[o + 0] = __fsub_rn(xp[n], cx);
        out[o + 1] = __fsub_rn(yp[n], cy);
        out[o + 2] = __fsub_rn(zp[n], cz);
    }
}

// ---------------------------------------------------------------------------
// Fallback knn (full scan) -- used only if ws_size is too small.
// ---------------------------------------------------------------------------
#define KNN_WPB_FB 4
__global__ __launch_bounds__(KNN_WPB_FB * 64) void knn_fallback(
    const float* __restrict__ in, const float* __restrict__ centers,
    float* __restrict__ out) {
    __shared__ u64 sbuf[KNN_WPB_FB][QCAP];

    const int wave = threadIdx.x >> 6;
    const int lane = threadIdx.x & 63;
    const int cid  = blockIdx.x * KNN_WPB_FB + wave;
    const int b    = cid >> 9;

    const float* xp = in + (size_t)b * 3 * NPTS;
    const float* yp = xp + NPTS;
    const float* zp = xp + 2 * NPTS;

    const float cx = centers[cid * 3 + 0];
    const float cy = centers[cid * 3 + 1];
    const float cz = centers[cid * 3 + 2];

    float x = xp[lane], y = yp[lane], z = zp[lane];
    u64 m = packdi(sq3(__fsub_rn(x, cx), __fsub_rn(y, cy), __fsub_rn(z, cz)), lane);
    m = lane_sort64(m, lane);
    u64 tau = shfl_u64(m, 31);
    int cnt = 0;

    int j = 1;
#pragma unroll 1
    for (; j + 3 < NPTS / 64; j += 4) {
        int n0 = j * 64 + lane, n1 = n0 + 64, n2 = n0 + 128, n3 = n0 + 192;
        float x0 = xp[n0], y0 = yp[n0], z0 = zp[n0];
        float x1 = xp[n1], y1 = yp[n1], z1 = zp[n1];
        float x2 = xp[n2], y2 = yp[n2], z2 = zp[n2];
        float x3 = xp[n3], y3 = yp[n3], z3 = zp[n3];
        knn_step(m, tau, cnt, sbuf[wave], x0, y0, z0, cx, cy, cz, n0, lane);
        knn_step(m, tau, cnt, sbuf[wave], x1, y1, z1, cx, cy, cz, n1, lane);
        knn_step(m, tau, cnt, sbuf[wave], x2, y2, z2, cx, cy, cz, n2, lane);
        knn_step(m, tau, cnt, sbuf[wave], x3, y3, z3, cx, cy, cz, n3, lane);
    }
    for (; j < NPTS / 64; ++j) {
        int n = j * 64 + lane;
        knn_step(m, tau, cnt, sbuf[wave], xp[n], yp[n], zp[n], cx, cy, cz, n, lane);
    }
    while (cnt > 0) {
        int take = cnt < 64 ? cnt : 64;
        u64 v = sbuf[wave][lane];
        u64 c = (lane < take) ? v : ~0ull;
        c = lane_sort64(c, lane);
        m = lane_merge64(m, c, lane);
        int rem = cnt - take;
        if (lane < rem) sbuf[wave][lane] = sbuf[wave][64 + lane];
        cnt = rem;
    }
    if (lane < KNN_K) {
        int n = (int)(u32)m;
        size_t o = (size_t)cid * (KNN_K * 3) + (size_t)lane * 3;
        out[o + 0] = __fsub_rn(xp[n], cx);
        out[o + 1] = __fsub_rn(yp[n], cy);
        out[o + 2] = __fsub_rn(zp[n], cz);
    }
}

extern "C" void kernel_launch(void* const* d_in, const int* in_sizes, int n_in,
                              void* d_out, int out_size, void* d_ws, size_t ws_size,
                              hipStream_t stream) {
    const float* in  = (const float*)d_in[0];
    float* out       = (float*)d_out;
    float* centers   = out + (size_t)BATCH * NGRP * KNN_K * 3;  // second output section

    const size_t need = (size_t)BATCH * WSF * sizeof(float);  // ~4.3 MB

    fps_kernel<<<BATCH, FPS_T, 0, stream>>>(in, centers);
    if (d_ws != nullptr && ws_size >= need) {
        build_kernel<<<BATCH, BT, 0, stream>>>(in, (float*)d_ws);
        knn_kernel<<<(BATCH * NGRP) / KNN_WPB, KNN_T, 0, stream>>>(
            in, centers, (const float*)d_ws, out);
    } else {
        knn_fallback<<<(BATCH * NGRP) / KNN_WPB_FB, KNN_WPB_FB * 64, 0, stream>>>(
            in, centers, out);
    }
}

// Round 11
// 528.303 us; speedup vs baseline: 1.0633x; 1.0633x over previous
//
#include <hip/hip_runtime.h>

typedef unsigned long long u64;
typedef unsigned int u32;
typedef float v2f __attribute__((ext_vector_type(2)));

// Problem constants (from reference setup_inputs / NUM_GROUP / GROUP_SIZE)
#define BATCH 32
#define NPTS  8192
#define NGRP  512
#define KNN_K 32

#define FPS_T 256                  // fps block (4 waves) -- champion config
#define FPS_W (FPS_T / 64)         // 4 waves
#define PPAIR (NPTS / FPS_T / 2)   // 16 point-PAIRS per thread

#define KNN_WPB 8                  // knn waves per block
#define KNN_T   (KNN_WPB * 64)     // 512 threads
#define QCAP    128                // per-wave LDS candidate buffer depth

#define NCH     (NPTS / 64)        // 128 sorted 64-point chunks per batch
#define GC      16                 // grid cells per axis (16^3 = 4096)
#define NCELL   (GC * GC * GC)
#define QB      512                // quantile-CDF bins per axis
#define CBT     256                // combined fps+build kernel threads (4 waves)
// Workspace layout per batch (floats): sx[8192] sy[8192] sz[8192] sidx[8192(u32)] aabb[128*6]
#define WSF     (4 * NPTS + NCH * 6)   // 33536 floats per batch

// Exact IEEE (no FMA contraction) squared distance: ((dx*dx + dy*dy) + dz*dz)
__device__ __forceinline__ float sq3(float dx, float dy, float dz) {
    return __fadd_rn(__fadd_rn(__fmul_rn(dx, dx), __fmul_rn(dy, dy)), __fmul_rn(dz, dz));
}

// d >= 0 always -> IEEE bits order-monotonic; u64 ascending == (d, idx) lex.
__device__ __forceinline__ u64 packdi(float d, int n) {
    return ((u64)__float_as_uint(d) << 32) | (u32)n;
}

__device__ __forceinline__ u64 umin64(u64 a, u64 b) { return a < b ? a : b; }
__device__ __forceinline__ u64 umax64(u64 a, u64 b) { return a > b ? a : b; }

__device__ __forceinline__ u64 shfl_xor_u64(u64 v, int m) {
    int lo = __shfl_xor((int)(u32)v, m, 64);
    int hi = __shfl_xor((int)(u32)(v >> 32), m, 64);
    return ((u64)(u32)hi << 32) | (u32)lo;
}

__device__ __forceinline__ u64 shfl_u64(u64 v, int src) {
    int lo = __shfl((int)(u32)v, src, 64);
    int hi = __shfl((int)(u32)(v >> 32), src, 64);
    return ((u64)(u32)hi << 32) | (u32)lo;
}

// ---- DPP wave-64 u64-max reduction (result valid in lane 63) --------------
// update_dpp(old=0, bound_ctrl=1): invalid-source lanes read 0; 0 is a safe
// identity (keys are max-reduced; 0 never beats a real candidate).
template <int CTRL>
__device__ __forceinline__ u64 dpp_max_step(u64 k) {
    u32 plo = (u32)__builtin_amdgcn_update_dpp(0, (int)(u32)k, CTRL, 0xF, 0xF, true);
    u32 phi = (u32)__builtin_amdgcn_update_dpp(0, (int)(u32)(k >> 32), CTRL, 0xF, 0xF, true);
    u64 p = ((u64)phi << 32) | plo;
    return k > p ? k : p;
}
__device__ __forceinline__ u64 dpp_wave_max(u64 k) {
    k = dpp_max_step<0x111>(k);  // row_shr:1
    k = dpp_max_step<0x112>(k);  // row_shr:2
    k = dpp_max_step<0x114>(k);  // row_shr:4
    k = dpp_max_step<0x118>(k);  // row_shr:8
    k = dpp_max_step<0x142>(k);  // row_bcast15
    k = dpp_max_step<0x143>(k);  // row_bcast31 -> lane63 = full wave
    return k;
}

// Cross-lane bitonic sort: one u64 per lane -> ascending by lane index.
__device__ __forceinline__ u64 lane_sort64(u64 v, int lane) {
#pragma unroll
    for (int k = 2; k <= 64; k <<= 1) {
#pragma unroll
        for (int j = k >> 1; j > 0; j >>= 1) {
            u64 p = shfl_xor_u64(v, j);
            bool keepmin = (((lane & k) == 0) == ((lane & j) == 0));
            u64 mn = umin64(v, p), mx = umax64(v, p);
            v = keepmin ? mn : mx;
        }
    }
    return v;
}

// m, c ascending-sorted across lanes -> lowest 64 of the 128, sorted.
__device__ __forceinline__ u64 lane_merge64(u64 m, u64 c, int lane) {
    u64 cr = shfl_xor_u64(c, 63);
    u64 z = umin64(m, cr);
#pragma unroll
    for (int dd = 32; dd > 0; dd >>= 1) {
        u64 p = shfl_xor_u64(z, dd);
        u64 mn = umin64(z, p), mx = umax64(z, p);
        z = (lane & dd) ? mx : mn;
    }
    return z;
}

// One knn scan step: tau-filter + ballot-compacted LDS append + batched flush
__device__ __forceinline__ void knn_step(u64& m, u64& tau, int& cnt, u64* sbuf,
                                         float x, float y, float z,
                                         float cx, float cy, float cz,
                                         int n, int lane) {
    float d = sq3(__fsub_rn(x, cx), __fsub_rn(y, cy), __fsub_rn(z, cz));
    u64 kk = packdi(d, n);
    bool cand = kk < tau;  // strict: excluded keys provably > global 32nd
    u64 mask = __ballot(cand);
    if (mask) {
        u32 below = __builtin_amdgcn_mbcnt_hi(
            (u32)(mask >> 32), __builtin_amdgcn_mbcnt_lo((u32)mask, 0));
        if (cand) sbuf[cnt + below] = kk;
        cnt += (int)__popcll(mask);
        if (cnt >= 64) {
            u64 c = sbuf[lane];
            c = lane_sort64(c, lane);
            m = lane_merge64(m, c, lane);
            tau = shfl_u64(m, 31);
            int rem = cnt - 64;
            if (lane < rem) sbuf[lane] = sbuf[64 + lane];
            cnt = rem;
        }
    }
}

__device__ __forceinline__ int qbin(float v) {  // 512 bins over [-4,4]
    int c = (int)((v + 4.0f) * 64.0f);
    c = c < 0 ? 0 : c;
    return c > (QB - 1) ? (QB - 1) : c;
}
__device__ __forceinline__ u32 part3_4(u32 v) {  // spread 4 bits to bits 0,3,6,9
    return (v & 1u) | ((v & 2u) << 2) | ((v & 4u) << 4) | ((v & 8u) << 6);
}

// LDS overlays for the combined kernel (block-uniform role -> union is safe)
struct FpsLds {
    float sx[NPTS]; float sy[NPTS]; float sz[NPTS];   // 96 KB
    u64 s_key[2][FPS_W];
    float s_out[NGRP * 3];                            // 6 KB
};
struct BldLds {
    u32 hist[NCELL];                                  // 16 KB
    u32 hq[3][QB];                                    // 6 KB
    float sxl[NPTS]; float syl[NPTS]; float szl[NPTS];// 96 KB
    u32 wtot[3][CBT / 64];
};

// ---------------------------------------------------------------------------
// fps_build_kernel: 64 blocks x 256 threads, block-uniform role split.
//  blocks [0,32):   FPS role -- BYTE-IDENTICAL champion loop (418 us, 132
//                   VGPR). No thread guards, no waits, no cross-block deps.
//  blocks [32,64):  build role -- quantile-warped Morton counting-sort +
//                   per-chunk AABBs, re-expressed for 256 threads and
//                   REGISTER-LIGHT (coords reloaded from L2 per pass instead
//                   of 96-element register arrays -> fps's 132-VGPR codegen
//                   is the kernel max). Scatter order differs from the
//                   512-thread build (thread mapping + atomic order) but all
//                   consumers are scan-order-independent lex selections ->
//                   output bits unaffected.
// Rationale: fps and build are data-independent; serializing them on the
// stream wasted build's whole duration. Roles never communicate -> no
// deadlock risk (unlike the abandoned R5-R8 fps||knn fusion, which also
// spilled to 88 VGPR via a thread-divergent guard; this kernel keeps
// blockDim == FPS_T so the champion body compiles unguarded).
// ---------------------------------------------------------------------------
__global__ __launch_bounds__(CBT) void fps_build_kernel(const float* __restrict__ in,
                                                        float* __restrict__ ws,
                                                        float* __restrict__ centers) {
#pragma clang fp contract(off)
    __shared__ alignas(16) char smem[sizeof(BldLds)];  // BldLds (121 KB) > FpsLds

    const int t = threadIdx.x;
    const int lane = t & 63;
    const int w = t >> 6;

    if (blockIdx.x < BATCH) {
        // ------------------------- FPS role (champion) --------------------
        FpsLds& S = *reinterpret_cast<FpsLds*>(smem);
        const int b = blockIdx.x;
        const float* xp = in + (size_t)b * 3 * NPTS;
        const float* yp = xp + NPTS;
        const float* zp = xp + 2 * NPTS;

        v2f xr[PPAIR], yr[PPAIR], zr[PPAIR], md[PPAIR];
#pragma unroll
        for (int i = 0; i < PPAIR; ++i) {
            int n = i * (2 * FPS_T) + 2 * t;       // pair covers points n, n+1
            xr[i] = *(const v2f*)(xp + n);
            yr[i] = *(const v2f*)(yp + n);
            zr[i] = *(const v2f*)(zp + n);
            *(v2f*)(S.sx + n) = xr[i];
            *(v2f*)(S.sy + n) = yr[i];
            *(v2f*)(S.sz + n) = zr[i];
            md[i] = (v2f){1e10f, 1e10f};
        }
        __syncthreads();

        int cur = 0;
        for (int r = 0; r < NGRP; ++r) {
            const float cx = S.sx[cur], cy = S.sy[cur], cz = S.sz[cur];
            if (t == 0) {  // idxs[r] is the PRE-update farthest -> buffer coords
                S.s_out[r * 3 + 0] = cx;
                S.s_out[r * 3 + 1] = cy;
                S.s_out[r * 3 + 2] = cz;
            }

            float bd0 = -1.0f, bd1 = -1.0f;
            int   bi0 = 0,     bi1 = 0;
#pragma unroll
            for (int i = 0; i < PPAIR; ++i) {
                v2f dx = xr[i] - cx;
                v2f dy = yr[i] - cy;
                v2f dz = zr[i] - cz;
                v2f dd = dx * dx + dy * dy + dz * dz;  // contract(off): 3 mul + 2 add
                md[i] = __builtin_elementwise_min(md[i], dd);
                int n = i * (2 * FPS_T) + 2 * t;
                if (md[i].x > bd0) { bd0 = md[i].x; bi0 = n; }      // strict >: first max
                if (md[i].y > bd1) { bd1 = md[i].y; bi1 = n + 1; }
            }
            // max (d, tie -> lowest n) == u64 max of (d_bits, ~n)
            u64 k0 = ((u64)__float_as_uint(bd0) << 32) | (u32)(~(u32)bi0);
            u64 k1 = ((u64)__float_as_uint(bd1) << 32) | (u32)(~(u32)bi1);
            u64 k = dpp_wave_max(umax64(k0, k1));
            if ((t & 63) == 63) S.s_key[r & 1][w] = k;  // lane 63 holds wave winner
            __syncthreads();
            u64 m = umax64(umax64(S.s_key[r & 1][0], S.s_key[r & 1][1]),
                           umax64(S.s_key[r & 1][2], S.s_key[r & 1][3]));
            cur = (int)(~(u32)m);  // recover winning index
        }

        __syncthreads();  // t0's last s_out writes
        float* cdst = centers + (size_t)b * NGRP * 3;
        for (int i = t; i < NGRP * 3; i += FPS_T) cdst[i] = S.s_out[i];
        return;
    }

    // --------------------------- build role -------------------------------
    BldLds& S = *reinterpret_cast<BldLds*>(smem);
    const int b = blockIdx.x - BATCH;
    const float* xp = in + (size_t)b * 3 * NPTS;
    const float* yp = xp + NPTS;
    const float* zp = xp + 2 * NPTS;
    float* wsb = ws + (size_t)b * WSF;
    float* ws_sx = wsb;
    float* ws_sy = wsb + NPTS;
    float* ws_sz = wsb + 2 * NPTS;
    u32*   ws_si = (u32*)(wsb + 3 * NPTS);
    float* ws_ab = wsb + 4 * NPTS;

    for (int i = t; i < NCELL; i += CBT) S.hist[i] = 0;
    for (int i = t; i < 3 * QB; i += CBT) (&S.hq[0][0])[i] = 0;
    __syncthreads();

    // pass 1: per-axis 512-bin histograms (coords reloaded -> register-light)
    for (int i = t; i < NPTS; i += CBT) {
        atomicAdd(&S.hq[0][qbin(xp[i])], 1u);
        atomicAdd(&S.hq[1][qbin(yp[i])], 1u);
        atomicAdd(&S.hq[2][qbin(zp[i])], 1u);
    }
    __syncthreads();

    // exclusive-scan each 512-bin histogram with 256 threads (bins 2t, 2t+1),
    // then convert in place to the quantile-cell LUT: cell = excl_cdf >> 9.
    {
        u32 va0 = S.hq[0][2 * t], vb0 = S.hq[0][2 * t + 1];
        u32 va1 = S.hq[1][2 * t], vb1 = S.hq[1][2 * t + 1];
        u32 va2 = S.hq[2][2 * t], vb2 = S.hq[2][2 * t + 1];
        u32 s0 = va0 + vb0, s1 = va1 + vb1, s2 = va2 + vb2;
        u32 x0 = s0, x1 = s1, x2 = s2;
#pragma unroll
        for (int d = 1; d < 64; d <<= 1) {
            u32 y0 = __shfl_up(x0, d, 64), y1 = __shfl_up(x1, d, 64), y2 = __shfl_up(x2, d, 64);
            if (lane >= d) { x0 += y0; x1 += y1; x2 += y2; }
        }
        if (lane == 63) { S.wtot[0][w] = x0; S.wtot[1][w] = x1; S.wtot[2][w] = x2; }
        __syncthreads();
        u32 b0 = 0, b1 = 0, b2 = 0;
        for (int j = 0; j < w; ++j) { b0 += S.wtot[0][j]; b1 += S.wtot[1][j]; b2 += S.wtot[2][j]; }
        u32 e0 = b0 + x0 - s0, e1 = b1 + x1 - s1, e2 = b2 + x2 - s2;
        S.hq[0][2 * t] = e0 >> 9;  S.hq[0][2 * t + 1] = (e0 + va0) >> 9;  // <= 15, 4-bit
        S.hq[1][2 * t] = e1 >> 9;  S.hq[1][2 * t + 1] = (e1 + va1) >> 9;
        S.hq[2][2 * t] = e2 >> 9;  S.hq[2][2 * t + 1] = (e2 + va2) >> 9;
    }
    __syncthreads();

    // pass 2: Morton code on warped cells -> counting histogram
    for (int i = t; i < NPTS; i += CBT) {
        int pc = (int)(part3_4(S.hq[0][qbin(xp[i])]) |
                       (part3_4(S.hq[1][qbin(yp[i])]) << 1) |
                       (part3_4(S.hq[2][qbin(zp[i])]) << 2));
        atomicAdd(&S.hist[pc], 1u);
    }
    __syncthreads();

    // exclusive scan of hist[4096]: 16 cells/thread + wave scan + cross-wave
    {
        u32 h[NCELL / CBT];
        u32 lsum = 0;
#pragma unroll
        for (int j = 0; j < NCELL / CBT; ++j) { h[j] = S.hist[t * (NCELL / CBT) + j]; lsum += h[j]; }
        u32 x = lsum;
#pragma unroll
        for (int d = 1; d < 64; d <<= 1) {
            u32 y = __shfl_up(x, d, 64);
            if (lane >= d) x += y;
        }
        if (lane == 63) S.wtot[0][w] = x;
        __syncthreads();
        u32 base = 0;
        for (int j = 0; j < w; ++j) base += S.wtot[0][j];
        u32 run = base + x - lsum;
#pragma unroll
        for (int j = 0; j < NCELL / CBT; ++j) {
            u32 c = h[j];
            S.hist[t * (NCELL / CBT) + j] = run;
            run += c;
        }
    }
    __syncthreads();

    // pass 3: scatter into LDS (coords) + global (orig index)
    for (int i = t; i < NPTS; i += CBT) {
        float X = xp[i], Y = yp[i], Z = zp[i];
        int pc = (int)(part3_4(S.hq[0][qbin(X)]) |
                       (part3_4(S.hq[1][qbin(Y)]) << 1) |
                       (part3_4(S.hq[2][qbin(Z)]) << 2));
        u32 pos = atomicAdd(&S.hist[pc], 1u);
        S.sxl[pos] = X; S.syl[pos] = Y; S.szl[pos] = Z;
        ws_si[pos] = (u32)i;
    }
    __syncthreads();

    // write sorted coords out, coalesced
    for (int i = t; i < NPTS; i += CBT) {
        ws_sx[i] = S.sxl[i]; ws_sy[i] = S.syl[i]; ws_sz[i] = S.szl[i];
    }
    // per-chunk AABB: 128 chunks / 4 waves
    for (int q = w; q < NCH; q += CBT / 64) {
        int p = q * 64 + lane;
        float X = S.sxl[p], Y = S.syl[p], Z = S.szl[p];
        float xlo = X, xhi = X, ylo = Y, yhi = Y, zlo = Z, zhi = Z;
#pragma unroll
        for (int d = 1; d < 64; d <<= 1) {
            xlo = fminf(xlo, __shfl_xor(xlo, d, 64)); xhi = fmaxf(xhi, __shfl_xor(xhi, d, 64));
            ylo = fminf(ylo, __shfl_xor(ylo, d, 64)); yhi = fmaxf(yhi, __shfl_xor(yhi, d, 64));
            zlo = fminf(zlo, __shfl_xor(zlo, d, 64)); zhi = fmaxf(zhi, __shfl_xor(zhi, d, 64));
        }
        if (lane == 0) {
            float* a = ws_ab + q * 6;
            a[0] = xlo; a[1] = xhi; a[2] = ylo; a[3] = yhi; a[4] = zlo; a[5] = zhi;
        }
    }
}

// ---------------------------------------------------------------------------
// kNN (R9 measured-best): chunk-pruned exact top-32. Per wave: 128 chunk
// AABB lower bounds (2/lane as (lb_bits<<32)|chunk u64 keys), DPP-min-pick
// nearest chunk, seed exact top-64, then pick+tau-filter until
// lb*0.999 > tau_d (sound skip). R10's static-sort variant was +6us ->
// reverted to this version.
// ---------------------------------------------------------------------------
__global__ __launch_bounds__(KNN_T) void knn_kernel(const float* __restrict__ in,
                                                    const float* __restrict__ centers,
                                                    const float* __restrict__ ws,
                                                    float* __restrict__ out) {
    __shared__ float s_ab[NCH * 6];      // 3 KB chunk AABBs (whole block same batch)
    __shared__ u64 sbuf[KNN_WPB][QCAP];  // 8 KB candidate buffers

    const int wave = threadIdx.x >> 6;
    const int lane = threadIdx.x & 63;
    const int cid  = blockIdx.x * KNN_WPB + wave;   // [0, B*G); 8 waves same batch
    const int b    = cid >> 9;                      // /NGRP

    const float* xp = in + (size_t)b * 3 * NPTS;
    const float* yp = xp + NPTS;
    const float* zp = xp + 2 * NPTS;
    const float* wsb = ws + (size_t)b * WSF;
    const float* sxs = wsb;
    const float* sys = wsb + NPTS;
    const float* szs = wsb + 2 * NPTS;
    const u32*   sidx = (const u32*)(wsb + 3 * NPTS);
    const float* ab = wsb + 4 * NPTS;

    for (int i = threadIdx.x; i < NCH * 6; i += KNN_T) s_ab[i] = ab[i];
    __syncthreads();

    const float cx = centers[cid * 3 + 0];
    const float cy = centers[cid * 3 + 1];
    const float cz = centers[cid * 3 + 2];

    // per-lane lower-bound keys for chunks lane and lane+64
    u64 k0, k1;
    {
        const float* a0 = &s_ab[lane * 6];
        float dx = fmaxf(fmaxf(__fsub_rn(a0[0], cx), __fsub_rn(cx, a0[1])), 0.0f);
        float dy = fmaxf(fmaxf(__fsub_rn(a0[2], cy), __fsub_rn(cy, a0[3])), 0.0f);
        float dz = fmaxf(fmaxf(__fsub_rn(a0[4], cz), __fsub_rn(cz, a0[5])), 0.0f);
        k0 = ((u64)__float_as_uint(dx * dx + dy * dy + dz * dz) << 32) | (u32)lane;
        const float* a1 = &s_ab[(lane + 64) * 6];
        dx = fmaxf(fmaxf(__fsub_rn(a1[0], cx), __fsub_rn(cx, a1[1])), 0.0f);
        dy = fmaxf(fmaxf(__fsub_rn(a1[2], cy), __fsub_rn(cy, a1[3])), 0.0f);
        dz = fmaxf(fmaxf(__fsub_rn(a1[4], cz), __fsub_rn(cz, a1[5])), 0.0f);
        k1 = ((u64)__float_as_uint(dx * dx + dy * dy + dz * dz) << 32) | (u32)(lane + 64);
    }

    u64 m, tau;
    int cnt = 0;

    // seed: nearest chunk, exact sorted top-64
    {
        u64 inv = dpp_wave_max(~umin64(k0, k1));
        u64 got = ~shfl_u64(inv, 63);
        int c = (int)(u32)got;
        int p = c * 64 + lane;
        float X = sxs[p], Y = sys[p], Z = szs[p];
        int n = (int)sidx[p];
        m = lane_sort64(packdi(sq3(__fsub_rn(X, cx), __fsub_rn(Y, cy), __fsub_rn(Z, cz)), n),
                        lane);
        tau = shfl_u64(m, 31);
        if (lane == (c & 63)) { if (c < 64) k0 = ~0ull; else k1 = ~0ull; }
    }

    // pick+filter loop: chunks in ascending lb order, sound early break
    for (int it = 1; it < NCH; ++it) {
        u64 inv = dpp_wave_max(~umin64(k0, k1));
        u64 got = ~shfl_u64(inv, 63);
        float lb = __uint_as_float((u32)(got >> 32));
        float tau_d = __uint_as_float((u32)(tau >> 32));
        if (lb * 0.999f > tau_d) break;  // all remaining chunks provably > 32nd
        int c = (int)(u32)got;
        int p = c * 64 + lane;
        float X = sxs[p], Y = sys[p], Z = szs[p];
        int n = (int)sidx[p];
        knn_step(m, tau, cnt, sbuf[wave], X, Y, Z, cx, cy, cz, n, lane);
        if (lane == (c & 63)) { if (c < 64) k0 = ~0ull; else k1 = ~0ull; }
    }

    // drain leftovers (<= 127 keys -> at most 2 batches)
    while (cnt > 0) {
        int take = cnt < 64 ? cnt : 64;
        u64 v = sbuf[wave][lane];
        u64 c = (lane < take) ? v : ~0ull;
        c = lane_sort64(c, lane);
        m = lane_merge64(m, c, lane);
        int rem = cnt - take;
        if (lane < rem) sbuf[wave][lane] = sbuf[wave][64 + lane];
        cnt = rem;
    }

    // lanes 0..31 hold the exact global top-32, ascending (== stable top_k)
    if (lane < KNN_K) {
        int n = (int)(u32)m;
        size_t o = (size_t)cid * (KNN_K * 3) + (size_t)lane * 3;
        out[o + 0] = __fsub_rn(xp[n], cx);
        out[o + 1] = __fsub_rn(yp[n], cy);
        out[o + 2] = __fsub_rn(zp[n], cz);
    }
}

// ---------------------------------------------------------------------------
// Fallback path (no workspace): standalone champion fps + full-scan knn.
// ---------------------------------------------------------------------------
__global__ __launch_bounds__(FPS_T) void fps_kernel(const float* __restrict__ in,
                                                    float* __restrict__ centers) {
#pragma clang fp contract(off)
    __shared__ float sx[NPTS];
    __shared__ float sy[NPTS];
    __shared__ float sz[NPTS];
    __shared__ u64 s_key[2][FPS_W];
    __shared__ float s_out[NGRP * 3];

    const int b = blockIdx.x;
    const int t = threadIdx.x;
    const int w = t >> 6;
    const float* xp = in + (size_t)b * 3 * NPTS;
    const float* yp = xp + NPTS;
    const float* zp = xp + 2 * NPTS;

    v2f xr[PPAIR], yr[PPAIR], zr[PPAIR], md[PPAIR];
#pragma unroll
    for (int i = 0; i < PPAIR; ++i) {
        int n = i * (2 * FPS_T) + 2 * t;
        xr[i] = *(const v2f*)(xp + n);
        yr[i] = *(const v2f*)(yp + n);
        zr[i] = *(const v2f*)(zp + n);
        *(v2f*)(sx + n) = xr[i];
        *(v2f*)(sy + n) = yr[i];
        *(v2f*)(sz + n) = zr[i];
        md[i] = (v2f){1e10f, 1e10f};
    }
    __syncthreads();

    int cur = 0;
    for (int r = 0; r < NGRP; ++r) {
        const float cx = sx[cur], cy = sy[cur], cz = sz[cur];
        if (t == 0) {
            s_out[r * 3 + 0] = cx;
            s_out[r * 3 + 1] = cy;
            s_out[r * 3 + 2] = cz;
        }
        float bd0 = -1.0f, bd1 = -1.0f;
        int   bi0 = 0,     bi1 = 0;
#pragma unroll
        for (int i = 0; i < PPAIR; ++i) {
            v2f dx = xr[i] - cx;
            v2f dy = yr[i] - cy;
            v2f dz = zr[i] - cz;
            v2f dd = dx * dx + dy * dy + dz * dz;
            md[i] = __builtin_elementwise_min(md[i], dd);
            int n = i * (2 * FPS_T) + 2 * t;
            if (md[i].x > bd0) { bd0 = md[i].x; bi0 = n; }
            if (md[i].y > bd1) { bd1 = md[i].y; bi1 = n + 1; }
        }
        u64 k0 = ((u64)__float_as_uint(bd0) << 32) | (u32)(~(u32)bi0);
        u64 k1 = ((u64)__float_as_uint(bd1) << 32) | (u32)(~(u32)bi1);
        u64 k = dpp_wave_max(umax64(k0, k1));
        if ((t & 63) == 63) s_key[r & 1][w] = k;
        __syncthreads();
        u64 m = umax64(umax64(s_key[r & 1][0], s_key[r & 1][1]),
                       umax64(s_key[r & 1][2], s_key[r & 1][3]));
        cur = (int)(~(u32)m);
    }

    __syncthreads();
    float* cdst = centers + (size_t)b * NGRP * 3;
    for (int i = t; i < NGRP * 3; i += FPS_T) cdst[i] = s_out[i];
}

#define KNN_WPB_FB 4
__global__ __launch_bounds__(KNN_WPB_FB * 64) void knn_fallback(
    const float* __restrict__ in, const float* __restrict__ centers,
    float* __restrict__ out) {
    __shared__ u64 sbuf[KNN_WPB_FB][QCAP];

    const int wave = threadIdx.x >> 6;
    const int lane = threadIdx.x & 63;
    const int cid  = blockIdx.x * KNN_WPB_FB + wave;
    const int b    = cid >> 9;

    const float* xp = in + (size_t)b * 3 * NPTS;
    const float* yp = xp + NPTS;
    const float* zp = xp + 2 * NPTS;

    const float cx = centers[cid * 3 + 0];
    const float cy = centers[cid * 3 + 1];
    const float cz = centers[cid * 3 + 2];

    float x = xp[lane], y = yp[lane], z = zp[lane];
    u64 m = packdi(sq3(__fsub_rn(x, cx), __fsub_rn(y, cy), __fsub_rn(z, cz)), lane);
    m = lane_sort64(m, lane);
    u64 tau = shfl_u64(m, 31);
    int cnt = 0;

    int j = 1;
#pragma unroll 1
    for (; j + 3 < NPTS / 64; j += 4) {
        int n0 = j * 64 + lane, n1 = n0 + 64, n2 = n0 + 128, n3 = n0 + 192;
        float x0 = xp[n0], y0 = yp[n0], z0 = zp[n0];
        float x1 = xp[n1], y1 = yp[n1], z1 = zp[n1];
        float x2 = xp[n2], y2 = yp[n2], z2 = zp[n2];
        float x3 = xp[n3], y3 = yp[n3], z3 = zp[n3];
        knn_step(m, tau, cnt, sbuf[wave], x0, y0, z0, cx, cy, cz, n0, lane);
        knn_step(m, tau, cnt, sbuf[wave], x1, y1, z1, cx, cy, cz, n1, lane);
        knn_step(m, tau, cnt, sbuf[wave], x2, y2, z2, cx, cy, cz, n2, lane);
        knn_step(m, tau, cnt, sbuf[wave], x3, y3, z3, cx, cy, cz, n3, lane);
    }
    for (; j < NPTS / 64; ++j) {
        int n = j * 64 + lane;
        knn_step(m, tau, cnt, sbuf[wave], xp[n], yp[n], zp[n], cx, cy, cz, n, lane);
    }
    while (cnt > 0) {
        int take = cnt < 64 ? cnt : 64;
        u64 v = sbuf[wave][lane];
        u64 c = (lane < take) ? v : ~0ull;
        c = lane_sort64(c, lane);
        m = lane_merge64(m, c, lane);
        int rem = cnt - take;
        if (lane < rem) sbuf[wave][lane] = sbuf[wave][64 + lane];
        cnt = rem;
    }
    if (lane < KNN_K) {
        int n = (int)(u32)m;
        size_t o = (size_t)cid * (KNN_K * 3) + (size_t)lane * 3;
        out[o + 0] = __fsub_rn(xp[n], cx);
        out[o + 1] = __fsub_rn(yp[n], cy);
        out[o + 2] = __fsub_rn(zp[n], cz);
    }
}

extern "C" void kernel_launch(void* const* d_in, const int* in_sizes, int n_in,
                              void* d_out, int out_size, void* d_ws, size_t ws_size,
                              hipStream_t stream) {
    const float* in  = (const float*)d_in[0];
    float* out       = (float*)d_out;
    float* centers   = out + (size_t)BATCH * NGRP * KNN_K * 3;  // second output section

    const size_t need = (size_t)BATCH * WSF * sizeof(float);  // ~4.3 MB

    if (d_ws != nullptr && ws_size >= need) {
        fps_build_kernel<<<2 * BATCH, CBT, 0, stream>>>(in, (float*)d_ws, centers);
        knn_kernel<<<(BATCH * NGRP) / KNN_WPB, KNN_T, 0, stream>>>(
            in, centers, (const float*)d_ws, out);
    } else {
        fps_kernel<<<BATCH, FPS_T, 0, stream>>>(in, centers);
        knn_fallback<<<(BATCH * NGRP) / KNN_WPB_FB, KNN_WPB_FB * 64, 0, stream>>>(
            in, centers, out);
    }
}